// Round 1
// baseline (851.488 us; speedup 1.0000x reference)
//
#include <hip/hip_runtime.h>

#define NN 100000
#define NE 1600000
#define DIN 128
#define HD 64
#define NP1 (NN + 1)
#define NB_SCAN 98   // ceil(100001/1024)

// ---------------- CSR build ----------------
__global__ __launch_bounds__(256) void k_hist(const int* __restrict__ dst, int* __restrict__ counts) {
    int e = blockIdx.x * 256 + threadIdx.x;
    atomicAdd(&counts[dst[e]], 1);
}

__global__ __launch_bounds__(256) void k_scan1(const int* __restrict__ counts, int* __restrict__ bsum) {
    __shared__ int ts[256];
    int t = threadIdx.x;
    int base = blockIdx.x * 1024 + t * 4;
    int s = 0;
#pragma unroll
    for (int j = 0; j < 4; ++j) { int ix = base + j; if (ix < NP1) s += counts[ix]; }
    ts[t] = s; __syncthreads();
    for (int o = 128; o; o >>= 1) { if (t < o) ts[t] += ts[t + o]; __syncthreads(); }
    if (t == 0) bsum[blockIdx.x] = ts[0];
}

__global__ __launch_bounds__(256) void k_scan2(int* __restrict__ bsum) {
    __shared__ int arr[128];
    int t = threadIdx.x;
    if (t < NB_SCAN) arr[t] = bsum[t];
    __syncthreads();
    if (t == 0) {
        int s = 0;
        for (int i = 0; i < NB_SCAN; ++i) { int x = arr[i]; arr[i] = s; s += x; }
    }
    __syncthreads();
    if (t < NB_SCAN) bsum[t] = arr[t];
}

__global__ __launch_bounds__(256) void k_scan3(const int* __restrict__ counts, const int* __restrict__ bsum,
                                               int* __restrict__ row_ptr) {
    __shared__ int ts[256];
    int t = threadIdx.x;
    int base = blockIdx.x * 1024 + t * 4;
    int v[4];
#pragma unroll
    for (int j = 0; j < 4; ++j) { int ix = base + j; v[j] = (ix < NP1) ? counts[ix] : 0; }
    int tsum = v[0] + v[1] + v[2] + v[3];
    ts[t] = tsum; __syncthreads();
    for (int o = 1; o < 256; o <<= 1) {
        int xv = 0;
        if (t >= o) xv = ts[t - o];
        __syncthreads();
        ts[t] += xv;
        __syncthreads();
    }
    int excl = (t == 0) ? 0 : ts[t - 1];
    int run = bsum[blockIdx.x] + excl;
#pragma unroll
    for (int j = 0; j < 4; ++j) {
        int ix = base + j;
        if (ix < NP1) row_ptr[ix] = run;
        run += v[j];
    }
}

__global__ __launch_bounds__(256) void k_scatter(const int* __restrict__ src, const int* __restrict__ dst,
                                                 const float* __restrict__ ew, const int* __restrict__ row_ptr,
                                                 int* __restrict__ cursor, int2* __restrict__ ep) {
    int e = blockIdx.x * 256 + threadIdx.x;
    int d = dst[e];
    int pos = row_ptr[d] + atomicAdd(&cursor[d], 1);
    ep[pos] = make_int2(src[e], __float_as_int(ew[e]));
}

// ---------------- SpMM: CSR wave-per-node ----------------
__global__ __launch_bounds__(256) void k_spmm(const int2* __restrict__ ep, const int* __restrict__ row_ptr,
                                              const float* __restrict__ h, float* __restrict__ hi) {
    int wid = threadIdx.x >> 6, lane = threadIdx.x & 63;
    int node = blockIdx.x * 4 + wid;
    int r0 = row_ptr[node], r1 = row_ptr[node + 1];
    float acc = 0.f;
    int e = r0;
    for (; e + 2 <= r1; e += 2) {
        int2 m0 = ep[e], m1 = ep[e + 1];
        float v0 = h[(size_t)m0.x * 64 + lane];
        float v1 = h[(size_t)m1.x * 64 + lane];
        acc += __int_as_float(m0.y) * v0;
        acc += __int_as_float(m1.y) * v1;
    }
    if (e < r1) {
        int2 m = ep[e];
        acc += __int_as_float(m.y) * h[(size_t)m.x * 64 + lane];
    }
    hi[(size_t)node * 64 + lane] = acc;
}

// ---------------- M_l = theta*W_l + (1-theta)*I ----------------
__global__ __launch_bounds__(256) void k_mprep(const float* __restrict__ gw, float* __restrict__ M, float4 th) {
    int idx = blockIdx.x * 256 + threadIdx.x;   // < 4*64*64
    int l = idx >> 12;
    int k = (idx >> 6) & 63;
    int c = idx & 63;
    float theta = (l == 0) ? th.x : (l == 1) ? th.y : (l == 2) ? th.z : th.w;
    float m = theta * gw[idx];
    if (k == c) m += (1.f - theta);
    M[idx] = m;
}

// ---------------- proj: h0 = x @ proj_w + proj_b ----------------
__global__ __launch_bounds__(256) void k_proj(const float* __restrict__ x, const float* __restrict__ W,
                                              const float* __restrict__ b, float* __restrict__ h0) {
    __shared__ float As[64 * 65];
    __shared__ float Bs[64 * 64];
    int tid = threadIdx.x;
    int cc = tid & 15, nc = tid >> 4;
    int tile0 = blockIdx.x * 64;
    float acc[4][4] = {{0.f}};
    for (int kc = 0; kc < DIN; kc += 64) {
        __syncthreads();
#pragma unroll
        for (int it = 0; it < 4; ++it) {
            int idx = tid + it * 256;
            int r = idx >> 4, q = (idx & 15) * 4;
            int gn = tile0 + r;
            float4 v = make_float4(0.f, 0.f, 0.f, 0.f);
            if (gn < NN) v = *(const float4*)&x[(size_t)gn * DIN + kc + q];
            As[r * 65 + q + 0] = v.x; As[r * 65 + q + 1] = v.y;
            As[r * 65 + q + 2] = v.z; As[r * 65 + q + 3] = v.w;
        }
#pragma unroll
        for (int it = 0; it < 4; ++it) {
            int idx = tid + it * 256;
            int k = idx >> 4, q = (idx & 15) * 4;
            *(float4*)&Bs[k * 64 + q] = *(const float4*)&W[(size_t)(kc + k) * 64 + q];
        }
        __syncthreads();
#pragma unroll 8
        for (int k = 0; k < 64; ++k) {
            float4 b4 = *(const float4*)&Bs[k * 64 + cc * 4];
            float a0 = As[(nc * 4 + 0) * 65 + k];
            float a1 = As[(nc * 4 + 1) * 65 + k];
            float a2 = As[(nc * 4 + 2) * 65 + k];
            float a3 = As[(nc * 4 + 3) * 65 + k];
            acc[0][0] += a0 * b4.x; acc[0][1] += a0 * b4.y; acc[0][2] += a0 * b4.z; acc[0][3] += a0 * b4.w;
            acc[1][0] += a1 * b4.x; acc[1][1] += a1 * b4.y; acc[1][2] += a1 * b4.z; acc[1][3] += a1 * b4.w;
            acc[2][0] += a2 * b4.x; acc[2][1] += a2 * b4.y; acc[2][2] += a2 * b4.z; acc[2][3] += a2 * b4.w;
            acc[3][0] += a3 * b4.x; acc[3][1] += a3 * b4.y; acc[3][2] += a3 * b4.z; acc[3][3] += a3 * b4.w;
        }
    }
#pragma unroll
    for (int i = 0; i < 4; ++i) {
        int gn = tile0 + nc * 4 + i;
        if (gn < NN) {
            float4 o;
            o.x = acc[i][0] + b[cc * 4 + 0];
            o.y = acc[i][1] + b[cc * 4 + 1];
            o.z = acc[i][2] + b[cc * 4 + 2];
            o.w = acc[i][3] + b[cc * 4 + 3];
            *(float4*)&h0[(size_t)gn * 64 + cc * 4] = o;
        }
    }
}

// ---------------- GCN combine: h = relu(supp @ M_l), supp = 0.9*hi + 0.1*h0 ----------------
__global__ __launch_bounds__(256) void k_combine(const float* __restrict__ hi, const float* __restrict__ h0,
                                                 const float* __restrict__ M, float* __restrict__ hout,
                                                 float* __restrict__ jk, int first, int write_h) {
    __shared__ float As[64 * 65];
    __shared__ float Bs[64 * 64];
    int tid = threadIdx.x;
    int cc = tid & 15, nc = tid >> 4;
    int tile0 = blockIdx.x * 64;
#pragma unroll
    for (int it = 0; it < 4; ++it) {
        int idx = tid + it * 256;
        int r = idx >> 4, q = (idx & 15) * 4;
        int gn = tile0 + r;
        float4 a = make_float4(0.f, 0.f, 0.f, 0.f);
        if (gn < NN) {
            float4 vh = *(const float4*)&hi[(size_t)gn * 64 + q];
            float4 v0 = *(const float4*)&h0[(size_t)gn * 64 + q];
            a.x = 0.9f * vh.x + 0.1f * v0.x;
            a.y = 0.9f * vh.y + 0.1f * v0.y;
            a.z = 0.9f * vh.z + 0.1f * v0.z;
            a.w = 0.9f * vh.w + 0.1f * v0.w;
        }
        As[r * 65 + q + 0] = a.x; As[r * 65 + q + 1] = a.y;
        As[r * 65 + q + 2] = a.z; As[r * 65 + q + 3] = a.w;
    }
#pragma unroll
    for (int it = 0; it < 4; ++it) {
        int idx = tid + it * 256;
        int k = idx >> 4, q = (idx & 15) * 4;
        *(float4*)&Bs[k * 64 + q] = *(const float4*)&M[k * 64 + q];
    }
    __syncthreads();
    float acc[4][4] = {{0.f}};
#pragma unroll 8
    for (int k = 0; k < 64; ++k) {
        float4 b4 = *(const float4*)&Bs[k * 64 + cc * 4];
        float a0 = As[(nc * 4 + 0) * 65 + k];
        float a1 = As[(nc * 4 + 1) * 65 + k];
        float a2 = As[(nc * 4 + 2) * 65 + k];
        float a3 = As[(nc * 4 + 3) * 65 + k];
        acc[0][0] += a0 * b4.x; acc[0][1] += a0 * b4.y; acc[0][2] += a0 * b4.z; acc[0][3] += a0 * b4.w;
        acc[1][0] += a1 * b4.x; acc[1][1] += a1 * b4.y; acc[1][2] += a1 * b4.z; acc[1][3] += a1 * b4.w;
        acc[2][0] += a2 * b4.x; acc[2][1] += a2 * b4.y; acc[2][2] += a2 * b4.z; acc[2][3] += a2 * b4.w;
        acc[3][0] += a3 * b4.x; acc[3][1] += a3 * b4.y; acc[3][2] += a3 * b4.z; acc[3][3] += a3 * b4.w;
    }
#pragma unroll
    for (int i = 0; i < 4; ++i) {
        int gn = tile0 + nc * 4 + i;
        if (gn >= NN) continue;
        float4 o;
        o.x = fmaxf(acc[i][0], 0.f);
        o.y = fmaxf(acc[i][1], 0.f);
        o.z = fmaxf(acc[i][2], 0.f);
        o.w = fmaxf(acc[i][3], 0.f);
        size_t p = (size_t)gn * 64 + cc * 4;
        if (write_h) *(float4*)&hout[p] = o;
        if (first) {
            *(float4*)&jk[p] = o;
        } else {
            float4 jv = *(const float4*)&jk[p];
            jv.x = fmaxf(jv.x, o.x); jv.y = fmaxf(jv.y, o.y);
            jv.z = fmaxf(jv.z, o.z); jv.w = fmaxf(jv.w, o.w);
            *(float4*)&jk[p] = jv;
        }
    }
}

// ---------------- fused MLP branch ----------------
__global__ __launch_bounds__(256) void k_mlp(const float* __restrict__ x,
        const float* __restrict__ W1, const float* __restrict__ b1,
        const float* __restrict__ g1, const float* __restrict__ be1,
        const float* __restrict__ W2, const float* __restrict__ b2,
        const float* __restrict__ g2, const float* __restrict__ be2,
        const float* __restrict__ w3, const float* __restrict__ b3,
        float* __restrict__ out) {
    __shared__ float As[64 * 65];
    __shared__ float Bs[64 * 64];
    __shared__ float2 red[64 * 17];
    int tid = threadIdx.x;
    int cc = tid & 15, nc = tid >> 4;
    int tile0 = blockIdx.x * 64;
    float acc[4][4] = {{0.f}};
    // GEMM1: x @ W1 (K=128, two chunks)
    for (int kc = 0; kc < DIN; kc += 64) {
        __syncthreads();
#pragma unroll
        for (int it = 0; it < 4; ++it) {
            int idx = tid + it * 256;
            int r = idx >> 4, q = (idx & 15) * 4;
            int gn = tile0 + r;
            float4 v = make_float4(0.f, 0.f, 0.f, 0.f);
            if (gn < NN) v = *(const float4*)&x[(size_t)gn * DIN + kc + q];
            As[r * 65 + q + 0] = v.x; As[r * 65 + q + 1] = v.y;
            As[r * 65 + q + 2] = v.z; As[r * 65 + q + 3] = v.w;
        }
#pragma unroll
        for (int it = 0; it < 4; ++it) {
            int idx = tid + it * 256;
            int k = idx >> 4, q = (idx & 15) * 4;
            *(float4*)&Bs[k * 64 + q] = *(const float4*)&W1[(size_t)(kc + k) * 64 + q];
        }
        __syncthreads();
#pragma unroll 8
        for (int k = 0; k < 64; ++k) {
            float4 b4 = *(const float4*)&Bs[k * 64 + cc * 4];
            float a0 = As[(nc * 4 + 0) * 65 + k];
            float a1 = As[(nc * 4 + 1) * 65 + k];
            float a2 = As[(nc * 4 + 2) * 65 + k];
            float a3 = As[(nc * 4 + 3) * 65 + k];
            acc[0][0] += a0 * b4.x; acc[0][1] += a0 * b4.y; acc[0][2] += a0 * b4.z; acc[0][3] += a0 * b4.w;
            acc[1][0] += a1 * b4.x; acc[1][1] += a1 * b4.y; acc[1][2] += a1 * b4.z; acc[1][3] += a1 * b4.w;
            acc[2][0] += a2 * b4.x; acc[2][1] += a2 * b4.y; acc[2][2] += a2 * b4.z; acc[2][3] += a2 * b4.w;
            acc[3][0] += a3 * b4.x; acc[3][1] += a3 * b4.y; acc[3][2] += a3 * b4.z; acc[3][3] += a3 * b4.w;
        }
    }
    __syncthreads();   // all As/Bs reads done
    // stats1 (bias folded in), restage Bs = W2
    float vals[4][4];
#pragma unroll
    for (int i = 0; i < 4; ++i) {
        float s = 0.f, q = 0.f;
#pragma unroll
        for (int j = 0; j < 4; ++j) {
            float v = acc[i][j] + b1[cc * 4 + j];
            vals[i][j] = v; s += v; q += v * v;
        }
        red[(nc * 4 + i) * 17 + cc] = make_float2(s, q);
    }
#pragma unroll
    for (int it = 0; it < 4; ++it) {
        int idx = tid + it * 256;
        int k = idx >> 4, q = (idx & 15) * 4;
        *(float4*)&Bs[k * 64 + q] = *(const float4*)&W2[(size_t)k * 64 + q];
    }
    __syncthreads();
    // LN1 + relu -> m1 into As
#pragma unroll
    for (int i = 0; i < 4; ++i) {
        int r = nc * 4 + i;
        float S = 0.f, Q = 0.f;
#pragma unroll
        for (int j = 0; j < 16; ++j) { float2 f = red[r * 17 + j]; S += f.x; Q += f.y; }
        float mu = S * (1.f / 64.f);
        float var = Q * (1.f / 64.f) - mu * mu;
        float rs = rsqrtf(var + 1e-5f);
#pragma unroll
        for (int j = 0; j < 4; ++j) {
            int c = cc * 4 + j;
            float m = (vals[i][j] - mu) * rs * g1[c] + be1[c];
            As[r * 65 + c] = fmaxf(m, 0.f);
        }
    }
    __syncthreads();
    // GEMM2: m1 @ W2
    float acc2[4][4] = {{0.f}};
#pragma unroll 8
    for (int k = 0; k < 64; ++k) {
        float4 b4 = *(const float4*)&Bs[k * 64 + cc * 4];
        float a0 = As[(nc * 4 + 0) * 65 + k];
        float a1 = As[(nc * 4 + 1) * 65 + k];
        float a2 = As[(nc * 4 + 2) * 65 + k];
        float a3 = As[(nc * 4 + 3) * 65 + k];
        acc2[0][0] += a0 * b4.x; acc2[0][1] += a0 * b4.y; acc2[0][2] += a0 * b4.z; acc2[0][3] += a0 * b4.w;
        acc2[1][0] += a1 * b4.x; acc2[1][1] += a1 * b4.y; acc2[1][2] += a1 * b4.z; acc2[1][3] += a1 * b4.w;
        acc2[2][0] += a2 * b4.x; acc2[2][1] += a2 * b4.y; acc2[2][2] += a2 * b4.z; acc2[2][3] += a2 * b4.w;
        acc2[3][0] += a3 * b4.x; acc2[3][1] += a3 * b4.y; acc2[3][2] += a3 * b4.z; acc2[3][3] += a3 * b4.w;
    }
    __syncthreads();
    // stats2
#pragma unroll
    for (int i = 0; i < 4; ++i) {
        float s = 0.f, q = 0.f;
#pragma unroll
        for (int j = 0; j < 4; ++j) {
            float v = acc2[i][j] + b2[cc * 4 + j];
            vals[i][j] = v; s += v; q += v * v;
        }
        red[(nc * 4 + i) * 17 + cc] = make_float2(s, q);
    }
    __syncthreads();
    // LN2 + relu + dot with w3 (partial over this thread's 4 cols)
    float part[4];
#pragma unroll
    for (int i = 0; i < 4; ++i) {
        int r = nc * 4 + i;
        float S = 0.f, Q = 0.f;
#pragma unroll
        for (int j = 0; j < 16; ++j) { float2 f = red[r * 17 + j]; S += f.x; Q += f.y; }
        float mu = S * (1.f / 64.f);
        float var = Q * (1.f / 64.f) - mu * mu;
        float rs = rsqrtf(var + 1e-5f);
        float p = 0.f;
#pragma unroll
        for (int j = 0; j < 4; ++j) {
            int c = cc * 4 + j;
            float m = fmaxf((vals[i][j] - mu) * rs * g2[c] + be2[c], 0.f);
            p += m * w3[c];
        }
        part[i] = p;
    }
    __syncthreads();
#pragma unroll
    for (int i = 0; i < 4; ++i) red[(nc * 4 + i) * 17 + cc] = make_float2(part[i], 0.f);
    __syncthreads();
    if (tid < 64) {
        float S = 0.f;
#pragma unroll
        for (int j = 0; j < 16; ++j) S += red[tid * 17 + j].x;
        int gn = tile0 + tid;
        if (gn < NN) out[gn] = 0.5f * (S + b3[0]);
    }
}

// ---------------- final: out += 0.5*(jk @ head_w + head_b) ----------------
__global__ __launch_bounds__(256) void k_final(const float* __restrict__ jk, const float* __restrict__ hw,
                                               const float* __restrict__ hb, float* __restrict__ out) {
    int wid = threadIdx.x >> 6, lane = threadIdx.x & 63;
    int n = blockIdx.x * 4 + wid;
    float v = jk[(size_t)n * 64 + lane] * hw[lane];
#pragma unroll
    for (int m = 32; m; m >>= 1) v += __shfl_xor(v, m);
    if (lane == 0) out[n] = out[n] + 0.5f * (v + hb[0]);
}

extern "C" void kernel_launch(void* const* d_in, const int* in_sizes, int n_in,
                              void* d_out, int out_size, void* d_ws, size_t ws_size,
                              hipStream_t stream) {
    const float* x      = (const float*)d_in[0];
    const float* ew     = (const float*)d_in[1];
    const float* proj_w = (const float*)d_in[2];
    const float* proj_b = (const float*)d_in[3];
    const float* gcn_w  = (const float*)d_in[4];
    const float* w1     = (const float*)d_in[5];
    const float* b1     = (const float*)d_in[6];
    const float* g1     = (const float*)d_in[7];
    const float* be1    = (const float*)d_in[8];
    const float* w2     = (const float*)d_in[9];
    const float* b2     = (const float*)d_in[10];
    const float* g2     = (const float*)d_in[11];
    const float* be2    = (const float*)d_in[12];
    const float* w3     = (const float*)d_in[13];
    const float* b3     = (const float*)d_in[14];
    const float* hw     = (const float*)d_in[15];
    const float* hb     = (const float*)d_in[16];
    const int*   ei     = (const int*)d_in[17];
    float* out = (float*)d_out;

    char* ws = (char*)d_ws;
    size_t off = 0;
    auto alloc = [&](size_t bytes) { size_t o = off; off += (bytes + 255) & ~(size_t)255; return o; };
    float* h0      = (float*)(ws + alloc((size_t)NN * 64 * 4));
    float* hc      = (float*)(ws + alloc((size_t)NN * 64 * 4));
    float* hi      = (float*)(ws + alloc((size_t)NN * 64 * 4));
    float* jk      = (float*)(ws + alloc((size_t)NN * 64 * 4));
    float* M       = (float*)(ws + alloc((size_t)4 * 64 * 64 * 4));
    int*   counts  = (int*)(ws + alloc((size_t)NP1 * 4));
    int*   cursor  = (int*)(ws + alloc((size_t)NN * 4));
    int*   bsum    = (int*)(ws + alloc(512));
    int*   row_ptr = (int*)(ws + alloc((size_t)NP1 * 4));
    int2*  ep      = (int2*)(ws + alloc((size_t)NE * 8));

    const int* srcv = ei;
    const int* dstv = ei + NE;

    hipMemsetAsync(counts, 0, (size_t)NP1 * 4, stream);
    hipMemsetAsync(cursor, 0, (size_t)NN * 4, stream);

    k_hist<<<NE / 256, 256, 0, stream>>>(dstv, counts);
    k_scan1<<<NB_SCAN, 256, 0, stream>>>(counts, bsum);
    k_scan2<<<1, 256, 0, stream>>>(bsum);
    k_scan3<<<NB_SCAN, 256, 0, stream>>>(counts, bsum, row_ptr);
    k_scatter<<<NE / 256, 256, 0, stream>>>(srcv, dstv, ew, row_ptr, cursor, ep);

    int tiles = (NN + 63) / 64;
    k_proj<<<tiles, 256, 0, stream>>>(x, proj_w, proj_b, h0);
    k_mlp<<<tiles, 256, 0, stream>>>(x, w1, b1, g1, be1, w2, b2, g2, be2, w3, b3, out);

    // theta_l = log(1/(l+1) + 1)
    k_mprep<<<64, 256, 0, stream>>>(gcn_w, M,
        make_float4(0.69314718055994531f, 0.40546510810816438f,
                    0.28768207245178085f, 0.22314355131420976f));

    const float* hprev = h0;
    for (int l = 0; l < 4; ++l) {
        k_spmm<<<NN / 4, 256, 0, stream>>>(ep, row_ptr, hprev, hi);
        k_combine<<<tiles, 256, 0, stream>>>(hi, h0, M + l * 4096, hc, jk,
                                             (l == 0) ? 1 : 0, (l < 3) ? 1 : 0);
        hprev = hc;
    }
    k_final<<<NN / 4, 256, 0, stream>>>(jk, hw, hb, out);
}

// Round 2
// 775.141 us; speedup vs baseline: 1.0985x; 1.0985x over previous
//
#include <hip/hip_runtime.h>

#define NN 100000
#define NE 1600000
#define DIN 128
#define HD 64
#define NP1 (NN + 1)
#define NB_SCAN 98   // ceil(100001/1024)

__device__ __forceinline__ unsigned short f2bf(float f) {
    unsigned int u = __float_as_uint(f);
    u += 0x7fff + ((u >> 16) & 1);     // round-to-nearest-even
    return (unsigned short)(u >> 16);
}
__device__ __forceinline__ float bf2f(unsigned int lo16) {
    return __uint_as_float(lo16 << 16);
}

// ---------------- CSR build ----------------
__global__ __launch_bounds__(256) void k_hist(const int* __restrict__ dst, int* __restrict__ counts) {
    int e = blockIdx.x * 256 + threadIdx.x;
    atomicAdd(&counts[dst[e]], 1);
}

__global__ __launch_bounds__(256) void k_scan1(const int* __restrict__ counts, int* __restrict__ bsum) {
    __shared__ int ts[256];
    int t = threadIdx.x;
    int base = blockIdx.x * 1024 + t * 4;
    int s = 0;
#pragma unroll
    for (int j = 0; j < 4; ++j) { int ix = base + j; if (ix < NP1) s += counts[ix]; }
    ts[t] = s; __syncthreads();
    for (int o = 128; o; o >>= 1) { if (t < o) ts[t] += ts[t + o]; __syncthreads(); }
    if (t == 0) bsum[blockIdx.x] = ts[0];
}

__global__ __launch_bounds__(256) void k_scan2(int* __restrict__ bsum) {
    __shared__ int arr[128];
    int t = threadIdx.x;
    if (t < NB_SCAN) arr[t] = bsum[t];
    __syncthreads();
    if (t == 0) {
        int s = 0;
        for (int i = 0; i < NB_SCAN; ++i) { int x = arr[i]; arr[i] = s; s += x; }
    }
    __syncthreads();
    if (t < NB_SCAN) bsum[t] = arr[t];
}

__global__ __launch_bounds__(256) void k_scan3(const int* __restrict__ counts, const int* __restrict__ bsum,
                                               int* __restrict__ row_ptr) {
    __shared__ int ts[256];
    int t = threadIdx.x;
    int base = blockIdx.x * 1024 + t * 4;
    int v[4];
#pragma unroll
    for (int j = 0; j < 4; ++j) { int ix = base + j; v[j] = (ix < NP1) ? counts[ix] : 0; }
    int tsum = v[0] + v[1] + v[2] + v[3];
    ts[t] = tsum; __syncthreads();
    for (int o = 1; o < 256; o <<= 1) {
        int xv = 0;
        if (t >= o) xv = ts[t - o];
        __syncthreads();
        ts[t] += xv;
        __syncthreads();
    }
    int excl = (t == 0) ? 0 : ts[t - 1];
    int run = bsum[blockIdx.x] + excl;
#pragma unroll
    for (int j = 0; j < 4; ++j) {
        int ix = base + j;
        if (ix < NP1) row_ptr[ix] = run;
        run += v[j];
    }
}

__global__ __launch_bounds__(256) void k_scatter(const int* __restrict__ src, const int* __restrict__ dst,
                                                 const float* __restrict__ ew, const int* __restrict__ row_ptr,
                                                 int* __restrict__ cursor, int2* __restrict__ ep) {
    int e = blockIdx.x * 256 + threadIdx.x;
    int d = dst[e];
    int pos = row_ptr[d] + atomicAdd(&cursor[d], 1);
    ep[pos] = make_int2(src[e], __float_as_int(ew[e]));
}

// ---------------- M_l = theta*W_l + (1-theta)*I ----------------
__global__ __launch_bounds__(256) void k_mprep(const float* __restrict__ gw, float* __restrict__ M, float4 th) {
    int idx = blockIdx.x * 256 + threadIdx.x;   // < 4*64*64
    int l = idx >> 12;
    int k = (idx >> 6) & 63;
    int c = idx & 63;
    float theta = (l == 0) ? th.x : (l == 1) ? th.y : (l == 2) ? th.z : th.w;
    float m = theta * gw[idx];
    if (k == c) m += (1.f - theta);
    M[idx] = m;
}

// ---------------- proj: h0 = x @ proj_w + proj_b  (fp32 + bf16 copy) ----------------
__global__ __launch_bounds__(256) void k_proj(const float* __restrict__ x, const float* __restrict__ W,
                                              const float* __restrict__ b, float* __restrict__ h0,
                                              unsigned short* __restrict__ h0b) {
    __shared__ float As[64 * 65];
    __shared__ float Bs[64 * 64];
    int tid = threadIdx.x;
    int cc = tid & 15, nc = tid >> 4;
    int tile0 = blockIdx.x * 64;
    float acc[4][4] = {{0.f}};
    for (int kc = 0; kc < DIN; kc += 64) {
        __syncthreads();
#pragma unroll
        for (int it = 0; it < 4; ++it) {
            int idx = tid + it * 256;
            int r = idx >> 4, q = (idx & 15) * 4;
            int gn = tile0 + r;
            float4 v = make_float4(0.f, 0.f, 0.f, 0.f);
            if (gn < NN) v = *(const float4*)&x[(size_t)gn * DIN + kc + q];
            As[r * 65 + q + 0] = v.x; As[r * 65 + q + 1] = v.y;
            As[r * 65 + q + 2] = v.z; As[r * 65 + q + 3] = v.w;
        }
#pragma unroll
        for (int it = 0; it < 4; ++it) {
            int idx = tid + it * 256;
            int k = idx >> 4, q = (idx & 15) * 4;
            *(float4*)&Bs[k * 64 + q] = *(const float4*)&W[(size_t)(kc + k) * 64 + q];
        }
        __syncthreads();
#pragma unroll 8
        for (int k = 0; k < 64; ++k) {
            float4 b4 = *(const float4*)&Bs[k * 64 + cc * 4];
            float a0 = As[(nc * 4 + 0) * 65 + k];
            float a1 = As[(nc * 4 + 1) * 65 + k];
            float a2 = As[(nc * 4 + 2) * 65 + k];
            float a3 = As[(nc * 4 + 3) * 65 + k];
            acc[0][0] += a0 * b4.x; acc[0][1] += a0 * b4.y; acc[0][2] += a0 * b4.z; acc[0][3] += a0 * b4.w;
            acc[1][0] += a1 * b4.x; acc[1][1] += a1 * b4.y; acc[1][2] += a1 * b4.z; acc[1][3] += a1 * b4.w;
            acc[2][0] += a2 * b4.x; acc[2][1] += a2 * b4.y; acc[2][2] += a2 * b4.z; acc[2][3] += a2 * b4.w;
            acc[3][0] += a3 * b4.x; acc[3][1] += a3 * b4.y; acc[3][2] += a3 * b4.z; acc[3][3] += a3 * b4.w;
        }
    }
#pragma unroll
    for (int i = 0; i < 4; ++i) {
        int gn = tile0 + nc * 4 + i;
        if (gn < NN) {
            float4 o;
            o.x = acc[i][0] + b[cc * 4 + 0];
            o.y = acc[i][1] + b[cc * 4 + 1];
            o.z = acc[i][2] + b[cc * 4 + 2];
            o.w = acc[i][3] + b[cc * 4 + 3];
            *(float4*)&h0[(size_t)gn * 64 + cc * 4] = o;
            ushort4 ob;
            ob.x = f2bf(o.x); ob.y = f2bf(o.y); ob.z = f2bf(o.z); ob.w = f2bf(o.w);
            *(ushort4*)&h0b[(size_t)gn * 64 + cc * 4] = ob;
        }
    }
}

// ---------------- fused layer: spmm (bf16 gather) + supp mix + GEMM(M_l) + relu + JK max ----------------
// block = 256 thr = 4 waves; block covers 64 nodes; wave handles 16 consecutive nodes, 2 nodes at a time
// (lanes 0-31 -> node A, lanes 32-63 -> node B; each lane covers 2 channels as packed bf16x2).
__global__ __launch_bounds__(256) void k_layer(const int2* __restrict__ ep, const int* __restrict__ row_ptr,
                                               const unsigned short* __restrict__ hb,   // bf16 h prev [N*64]
                                               const float* __restrict__ h0,            // fp32 h0
                                               const float* __restrict__ M,             // 64x64
                                               unsigned short* __restrict__ hb_out,     // bf16 h out
                                               float* __restrict__ jk, int first, int write_h) {
    __shared__ float As[64 * 65];
    __shared__ float Bs[64 * 64];
    int tid = threadIdx.x;
    int wid = tid >> 6, lane = tid & 63;
    int half = lane >> 5, hl = lane & 31;
    int tile0 = blockIdx.x * 64;

    // stage Bs = M
#pragma unroll
    for (int it = 0; it < 4; ++it) {
        int idx = tid + it * 256;
        int k = idx >> 4, q = (idx & 15) * 4;
        *(float4*)&Bs[k * 64 + q] = *(const float4*)&M[k * 64 + q];
    }

    // spmm + mix phase
#pragma unroll 1
    for (int i = 0; i < 8; ++i) {
        int r = wid * 16 + i * 2 + half;       // row in tile, 0..63
        int node = tile0 + r;
        float ax = 0.f, ay = 0.f;
        if (node < NN) {
            int r0 = row_ptr[node], r1 = row_ptr[node + 1];
            int e = r0;
            for (; e + 4 <= r1; e += 4) {
                int2 m0 = ep[e], m1 = ep[e + 1], m2 = ep[e + 2], m3 = ep[e + 3];
                unsigned int p0 = *(const unsigned int*)&hb[(size_t)m0.x * 64 + hl * 2];
                unsigned int p1 = *(const unsigned int*)&hb[(size_t)m1.x * 64 + hl * 2];
                unsigned int p2 = *(const unsigned int*)&hb[(size_t)m2.x * 64 + hl * 2];
                unsigned int p3 = *(const unsigned int*)&hb[(size_t)m3.x * 64 + hl * 2];
                float w0 = __int_as_float(m0.y), w1 = __int_as_float(m1.y);
                float w2 = __int_as_float(m2.y), w3 = __int_as_float(m3.y);
                ax += w0 * bf2f(p0 & 0xffffu); ay += w0 * bf2f(p0 >> 16);
                ax += w1 * bf2f(p1 & 0xffffu); ay += w1 * bf2f(p1 >> 16);
                ax += w2 * bf2f(p2 & 0xffffu); ay += w2 * bf2f(p2 >> 16);
                ax += w3 * bf2f(p3 & 0xffffu); ay += w3 * bf2f(p3 >> 16);
            }
            for (; e < r1; ++e) {
                int2 m = ep[e];
                unsigned int p = *(const unsigned int*)&hb[(size_t)m.x * 64 + hl * 2];
                float w = __int_as_float(m.y);
                ax += w * bf2f(p & 0xffffu); ay += w * bf2f(p >> 16);
            }
            float2 h0v = *(const float2*)&h0[(size_t)node * 64 + hl * 2];
            ax = 0.9f * ax + 0.1f * h0v.x;
            ay = 0.9f * ay + 0.1f * h0v.y;
        }
        As[r * 65 + hl * 2 + 0] = ax;
        As[r * 65 + hl * 2 + 1] = ay;
    }
    __syncthreads();

    // GEMM: supp @ M
    int cc = tid & 15, nc = tid >> 4;
    float acc[4][4] = {{0.f}};
#pragma unroll 8
    for (int k = 0; k < 64; ++k) {
        float4 b4 = *(const float4*)&Bs[k * 64 + cc * 4];
        float a0 = As[(nc * 4 + 0) * 65 + k];
        float a1 = As[(nc * 4 + 1) * 65 + k];
        float a2 = As[(nc * 4 + 2) * 65 + k];
        float a3 = As[(nc * 4 + 3) * 65 + k];
        acc[0][0] += a0 * b4.x; acc[0][1] += a0 * b4.y; acc[0][2] += a0 * b4.z; acc[0][3] += a0 * b4.w;
        acc[1][0] += a1 * b4.x; acc[1][1] += a1 * b4.y; acc[1][2] += a1 * b4.z; acc[1][3] += a1 * b4.w;
        acc[2][0] += a2 * b4.x; acc[2][1] += a2 * b4.y; acc[2][2] += a2 * b4.z; acc[2][3] += a2 * b4.w;
        acc[3][0] += a3 * b4.x; acc[3][1] += a3 * b4.y; acc[3][2] += a3 * b4.z; acc[3][3] += a3 * b4.w;
    }
#pragma unroll
    for (int i = 0; i < 4; ++i) {
        int gn = tile0 + nc * 4 + i;
        if (gn >= NN) continue;
        float4 o;
        o.x = fmaxf(acc[i][0], 0.f);
        o.y = fmaxf(acc[i][1], 0.f);
        o.z = fmaxf(acc[i][2], 0.f);
        o.w = fmaxf(acc[i][3], 0.f);
        size_t p = (size_t)gn * 64 + cc * 4;
        if (write_h) {
            ushort4 ob;
            ob.x = f2bf(o.x); ob.y = f2bf(o.y); ob.z = f2bf(o.z); ob.w = f2bf(o.w);
            *(ushort4*)&hb_out[p] = ob;
        }
        if (first) {
            *(float4*)&jk[p] = o;
        } else {
            float4 jv = *(const float4*)&jk[p];
            jv.x = fmaxf(jv.x, o.x); jv.y = fmaxf(jv.y, o.y);
            jv.z = fmaxf(jv.z, o.z); jv.w = fmaxf(jv.w, o.w);
            *(float4*)&jk[p] = jv;
        }
    }
}

// ---------------- fused MLP branch ----------------
__global__ __launch_bounds__(256) void k_mlp(const float* __restrict__ x,
        const float* __restrict__ W1, const float* __restrict__ b1,
        const float* __restrict__ g1, const float* __restrict__ be1,
        const float* __restrict__ W2, const float* __restrict__ b2,
        const float* __restrict__ g2, const float* __restrict__ be2,
        const float* __restrict__ w3, const float* __restrict__ b3,
        float* __restrict__ out) {
    __shared__ float As[64 * 65];
    __shared__ float Bs[64 * 64];
    __shared__ float2 red[64 * 17];
    int tid = threadIdx.x;
    int cc = tid & 15, nc = tid >> 4;
    int tile0 = blockIdx.x * 64;
    float acc[4][4] = {{0.f}};
    for (int kc = 0; kc < DIN; kc += 64) {
        __syncthreads();
#pragma unroll
        for (int it = 0; it < 4; ++it) {
            int idx = tid + it * 256;
            int r = idx >> 4, q = (idx & 15) * 4;
            int gn = tile0 + r;
            float4 v = make_float4(0.f, 0.f, 0.f, 0.f);
            if (gn < NN) v = *(const float4*)&x[(size_t)gn * DIN + kc + q];
            As[r * 65 + q + 0] = v.x; As[r * 65 + q + 1] = v.y;
            As[r * 65 + q + 2] = v.z; As[r * 65 + q + 3] = v.w;
        }
#pragma unroll
        for (int it = 0; it < 4; ++it) {
            int idx = tid + it * 256;
            int k = idx >> 4, q = (idx & 15) * 4;
            *(float4*)&Bs[k * 64 + q] = *(const float4*)&W1[(size_t)(kc + k) * 64 + q];
        }
        __syncthreads();
#pragma unroll 8
        for (int k = 0; k < 64; ++k) {
            float4 b4 = *(const float4*)&Bs[k * 64 + cc * 4];
            float a0 = As[(nc * 4 + 0) * 65 + k];
            float a1 = As[(nc * 4 + 1) * 65 + k];
            float a2 = As[(nc * 4 + 2) * 65 + k];
            float a3 = As[(nc * 4 + 3) * 65 + k];
            acc[0][0] += a0 * b4.x; acc[0][1] += a0 * b4.y; acc[0][2] += a0 * b4.z; acc[0][3] += a0 * b4.w;
            acc[1][0] += a1 * b4.x; acc[1][1] += a1 * b4.y; acc[1][2] += a1 * b4.z; acc[1][3] += a1 * b4.w;
            acc[2][0] += a2 * b4.x; acc[2][1] += a2 * b4.y; acc[2][2] += a2 * b4.z; acc[2][3] += a2 * b4.w;
            acc[3][0] += a3 * b4.x; acc[3][1] += a3 * b4.y; acc[3][2] += a3 * b4.z; acc[3][3] += a3 * b4.w;
        }
    }
    __syncthreads();
    float vals[4][4];
#pragma unroll
    for (int i = 0; i < 4; ++i) {
        float s = 0.f, q = 0.f;
#pragma unroll
        for (int j = 0; j < 4; ++j) {
            float v = acc[i][j] + b1[cc * 4 + j];
            vals[i][j] = v; s += v; q += v * v;
        }
        red[(nc * 4 + i) * 17 + cc] = make_float2(s, q);
    }
#pragma unroll
    for (int it = 0; it < 4; ++it) {
        int idx = tid + it * 256;
        int k = idx >> 4, q = (idx & 15) * 4;
        *(float4*)&Bs[k * 64 + q] = *(const float4*)&W2[(size_t)k * 64 + q];
    }
    __syncthreads();
#pragma unroll
    for (int i = 0; i < 4; ++i) {
        int r = nc * 4 + i;
        float S = 0.f, Q = 0.f;
#pragma unroll
        for (int j = 0; j < 16; ++j) { float2 f = red[r * 17 + j]; S += f.x; Q += f.y; }
        float mu = S * (1.f / 64.f);
        float var = Q * (1.f / 64.f) - mu * mu;
        float rs = rsqrtf(var + 1e-5f);
#pragma unroll
        for (int j = 0; j < 4; ++j) {
            int c = cc * 4 + j;
            float m = (vals[i][j] - mu) * rs * g1[c] + be1[c];
            As[r * 65 + c] = fmaxf(m, 0.f);
        }
    }
    __syncthreads();
    float acc2[4][4] = {{0.f}};
#pragma unroll 8
    for (int k = 0; k < 64; ++k) {
        float4 b4 = *(const float4*)&Bs[k * 64 + cc * 4];
        float a0 = As[(nc * 4 + 0) * 65 + k];
        float a1 = As[(nc * 4 + 1) * 65 + k];
        float a2 = As[(nc * 4 + 2) * 65 + k];
        float a3 = As[(nc * 4 + 3) * 65 + k];
        acc2[0][0] += a0 * b4.x; acc2[0][1] += a0 * b4.y; acc2[0][2] += a0 * b4.z; acc2[0][3] += a0 * b4.w;
        acc2[1][0] += a1 * b4.x; acc2[1][1] += a1 * b4.y; acc2[1][2] += a1 * b4.z; acc2[1][3] += a1 * b4.w;
        acc2[2][0] += a2 * b4.x; acc2[2][1] += a2 * b4.y; acc2[2][2] += a2 * b4.z; acc2[2][3] += a2 * b4.w;
        acc2[3][0] += a3 * b4.x; acc2[3][1] += a3 * b4.y; acc2[3][2] += a3 * b4.z; acc2[3][3] += a3 * b4.w;
    }
    __syncthreads();
#pragma unroll
    for (int i = 0; i < 4; ++i) {
        float s = 0.f, q = 0.f;
#pragma unroll
        for (int j = 0; j < 4; ++j) {
            float v = acc2[i][j] + b2[cc * 4 + j];
            vals[i][j] = v; s += v; q += v * v;
        }
        red[(nc * 4 + i) * 17 + cc] = make_float2(s, q);
    }
    __syncthreads();
    float part[4];
#pragma unroll
    for (int i = 0; i < 4; ++i) {
        int r = nc * 4 + i;
        float S = 0.f, Q = 0.f;
#pragma unroll
        for (int j = 0; j < 16; ++j) { float2 f = red[r * 17 + j]; S += f.x; Q += f.y; }
        float mu = S * (1.f / 64.f);
        float var = Q * (1.f / 64.f) - mu * mu;
        float rs = rsqrtf(var + 1e-5f);
        float p = 0.f;
#pragma unroll
        for (int j = 0; j < 4; ++j) {
            int c = cc * 4 + j;
            float m = fmaxf((vals[i][j] - mu) * rs * g2[c] + be2[c], 0.f);
            p += m * w3[c];
        }
        part[i] = p;
    }
    __syncthreads();
#pragma unroll
    for (int i = 0; i < 4; ++i) red[(nc * 4 + i) * 17 + cc] = make_float2(part[i], 0.f);
    __syncthreads();
    if (tid < 64) {
        float S = 0.f;
#pragma unroll
        for (int j = 0; j < 16; ++j) S += red[tid * 17 + j].x;
        int gn = tile0 + tid;
        if (gn < NN) out[gn] = 0.5f * (S + b3[0]);
    }
}

// ---------------- final: out += 0.5*(jk @ head_w + head_b) ----------------
__global__ __launch_bounds__(256) void k_final(const float* __restrict__ jk, const float* __restrict__ hw,
                                               const float* __restrict__ hb, float* __restrict__ out) {
    int wid = threadIdx.x >> 6, lane = threadIdx.x & 63;
    int n = blockIdx.x * 4 + wid;
    float v = jk[(size_t)n * 64 + lane] * hw[lane];
#pragma unroll
    for (int m = 32; m; m >>= 1) v += __shfl_xor(v, m);
    if (lane == 0) out[n] = out[n] + 0.5f * (v + hb[0]);
}

extern "C" void kernel_launch(void* const* d_in, const int* in_sizes, int n_in,
                              void* d_out, int out_size, void* d_ws, size_t ws_size,
                              hipStream_t stream) {
    const float* x      = (const float*)d_in[0];
    const float* ew     = (const float*)d_in[1];
    const float* proj_w = (const float*)d_in[2];
    const float* proj_b = (const float*)d_in[3];
    const float* gcn_w  = (const float*)d_in[4];
    const float* w1     = (const float*)d_in[5];
    const float* b1     = (const float*)d_in[6];
    const float* g1     = (const float*)d_in[7];
    const float* be1    = (const float*)d_in[8];
    const float* w2     = (const float*)d_in[9];
    const float* b2     = (const float*)d_in[10];
    const float* g2     = (const float*)d_in[11];
    const float* be2    = (const float*)d_in[12];
    const float* w3     = (const float*)d_in[13];
    const float* b3     = (const float*)d_in[14];
    const float* hw     = (const float*)d_in[15];
    const float* hb     = (const float*)d_in[16];
    const int*   ei     = (const int*)d_in[17];
    float* out = (float*)d_out;

    char* ws = (char*)d_ws;
    size_t off = 0;
    auto alloc = [&](size_t bytes) { size_t o = off; off += (bytes + 255) & ~(size_t)255; return o; };
    float* h0      = (float*)(ws + alloc((size_t)NN * 64 * 4));
    float* jk      = (float*)(ws + alloc((size_t)NN * 64 * 4));
    unsigned short* hbA = (unsigned short*)(ws + alloc((size_t)NN * 64 * 2));
    unsigned short* hbB = (unsigned short*)(ws + alloc((size_t)NN * 64 * 2));
    float* M       = (float*)(ws + alloc((size_t)4 * 64 * 64 * 4));
    int*   counts  = (int*)(ws + alloc((size_t)NP1 * 4));
    int*   cursor  = (int*)(ws + alloc((size_t)NN * 4));
    int*   bsum    = (int*)(ws + alloc(512));
    int*   row_ptr = (int*)(ws + alloc((size_t)NP1 * 4));
    int2*  ep      = (int2*)(ws + alloc((size_t)NE * 8));

    const int* srcv = ei;
    const int* dstv = ei + NE;

    hipMemsetAsync(counts, 0, (size_t)NP1 * 4, stream);
    hipMemsetAsync(cursor, 0, (size_t)NN * 4, stream);

    k_hist<<<NE / 256, 256, 0, stream>>>(dstv, counts);
    k_scan1<<<NB_SCAN, 256, 0, stream>>>(counts, bsum);
    k_scan2<<<1, 256, 0, stream>>>(bsum);
    k_scan3<<<NB_SCAN, 256, 0, stream>>>(counts, bsum, row_ptr);
    k_scatter<<<NE / 256, 256, 0, stream>>>(srcv, dstv, ew, row_ptr, cursor, ep);

    int tiles = (NN + 63) / 64;
    k_proj<<<tiles, 256, 0, stream>>>(x, proj_w, proj_b, h0, hbA);
    k_mlp<<<tiles, 256, 0, stream>>>(x, w1, b1, g1, be1, w2, b2, g2, be2, w3, b3, out);

    // theta_l = log(1/(l+1) + 1)
    k_mprep<<<64, 256, 0, stream>>>(gcn_w, M,
        make_float4(0.69314718055994531f, 0.40546510810816438f,
                    0.28768207245178085f, 0.22314355131420976f));

    // layer 0: A -> B, 1: B -> A, 2: A -> B, 3: B -> (none)
    k_layer<<<tiles, 256, 0, stream>>>(ep, row_ptr, hbA, h0, M + 0 * 4096, hbB, jk, 1, 1);
    k_layer<<<tiles, 256, 0, stream>>>(ep, row_ptr, hbB, h0, M + 1 * 4096, hbA, jk, 0, 1);
    k_layer<<<tiles, 256, 0, stream>>>(ep, row_ptr, hbA, h0, M + 2 * 4096, hbB, jk, 0, 1);
    k_layer<<<tiles, 256, 0, stream>>>(ep, row_ptr, hbB, h0, M + 3 * 4096, hbA, jk, 0, 0);

    k_final<<<NN / 4, 256, 0, stream>>>(jk, hw, hb, out);
}